// Round 7
// baseline (40.342 us; speedup 1.0000x reference)
//
#include <hip/hip_runtime.h>

#define NN 10000    // nodes
#define NE 25000    // edges
#define DF 128      // features
#define SB 256      // block size
#define NBLK ((NE + SB - 1) / SB)          // 98 scan blocks
#define NEWXB ((NE * 32 + SB - 1) / SB)    // 3125 newx blocks

// ---------------------------------------------------------------------------
// K1: tiny init — head[] = -1, lookback flags = 0. Off the heavy path.
// ---------------------------------------------------------------------------
__global__ void k_init(int* __restrict__ head, int* __restrict__ gFlag) {
    int tid = blockIdx.x * blockDim.x + threadIdx.x;
    if (tid < NN) head[tid] = -1;
    if (tid < NBLK) gFlag[tid] = 0;
}

// ---------------------------------------------------------------------------
// K2: per-node linked lists in one pass.
// ---------------------------------------------------------------------------
__global__ void k_link(const int* __restrict__ c0,
                       int* __restrict__ head, int* __restrict__ nxt) {
    int j = blockIdx.x * blockDim.x + threadIdx.x;
    if (j >= NE) return;
    nxt[j] = atomicExch(&head[c0[j]], j);
}

// ---------------------------------------------------------------------------
// K3: ONE dispatch, two block roles:
//  blocks [0, NBLK)        : fused cnt_edge + decoupled-lookback exclusive
//                            scan -> rowStart[0..NE]
//  blocks [NBLK, NBLK+NEWXB): new_x[e] = ((x[u]+x[v])*0.5 + ea[e])*0.5
// The 98 scan blocks publish flag=blockSum+1 then spin on predecessors; all
// fit co-resident and newx blocks always retire -> eventual residency -> no
// deadlock. newx overlaps the scan's latency instead of serializing before it.
// ---------------------------------------------------------------------------
__global__ __launch_bounds__(SB) void k_scan_newx(const float* __restrict__ x,
                                                  const float* __restrict__ ea,
                                                  const int* __restrict__ c0,
                                                  const int* __restrict__ c1,
                                                  const int* __restrict__ head,
                                                  const int* __restrict__ nxt,
                                                  int* __restrict__ gFlag,
                                                  int* __restrict__ rowStart,
                                                  float* __restrict__ out) {
    int b = blockIdx.x, t = threadIdx.x;

    if (b >= NBLK) {
        // ---- newx role ----
        int tid = (b - NBLK) * SB + t;
        if (tid >= NE * 32) return;
        int e = tid >> 5, q = tid & 31;
        int u = c0[e], v = c1[e];
        float4 a  = ((const float4*)(x + (size_t)u * DF))[q];
        float4 bb = ((const float4*)(x + (size_t)v * DF))[q];
        float4 c  = ((const float4*)(ea + (size_t)e * DF))[q];
        float4 r;
        r.x = ((a.x + bb.x) * 0.5f + c.x) * 0.5f;
        r.y = ((a.y + bb.y) * 0.5f + c.y) * 0.5f;
        r.z = ((a.z + bb.z) * 0.5f + c.z) * 0.5f;
        r.w = ((a.w + bb.w) * 0.5f + c.w) * 0.5f;
        ((float4*)(out + (size_t)e * DF))[q] = r;
        return;
    }

    // ---- cnt + scan role ----
    __shared__ int sc[SB];
    __shared__ int sr[SB];
    int i = b * SB + t;
    int cnt = 0;
    if (i < NE) {
        int u = c0[i], v = c1[i];
        for (int j = head[v]; j != -1; j = nxt[j])
            if (c1[j] != u) ++cnt;
    }
    sc[t] = cnt;
    __syncthreads();
    for (int off = 1; off < SB; off <<= 1) {
        int add = (t >= off) ? sc[t - off] : 0;
        __syncthreads();
        sc[t] += add;
        __syncthreads();
    }
    int blockSum = sc[SB - 1];
    if (t == 0) atomicExch(&gFlag[b], blockSum + 1);   // publish
    int val = 0;
    if (t < b) {                                       // parallel lookback
        int v2;
        do { v2 = atomicAdd(&gFlag[t], 0); } while (v2 == 0);
        val = v2 - 1;
    }
    sr[t] = val;
    __syncthreads();
    for (int off = SB / 2; off > 0; off >>= 1) {
        if (t < off) sr[t] += sr[t + off];
        __syncthreads();
    }
    int base = sr[0];
    if (i < NE) rowStart[i] = base + sc[t] - cnt;      // exclusive
    if (b == NBLK - 1 && t == 0) rowStart[NE] = base + blockSum;
}

// ---------------------------------------------------------------------------
// K4: one wave per edge i (wave-uniform i).
//  - single list walk: lane l owns element l; rank-by-value via shfl loop.
//  - attr: wave writes TWO identical rows per store (float4/lane, 1KB/inst).
// ---------------------------------------------------------------------------
__global__ void k_emit(const float* __restrict__ newx,
                       const int* __restrict__ c0, const int* __restrict__ c1,
                       const int* __restrict__ head, const int* __restrict__ nxt,
                       const int* __restrict__ rowStart,
                       float* __restrict__ outRows, float* __restrict__ outCols,
                       float* __restrict__ outAttr) {
    int gtid = blockIdx.x * blockDim.x + threadIdx.x;
    int i = gtid >> 6, lane = gtid & 63;
    if (i >= NE) return;
    int base = rowStart[i];
    int cnt  = rowStart[i + 1] - base;
    if (cnt == 0) return;
    int u = c0[i], v = c1[i];

    // walk list once; lane l records element l
    int myj = -1, B = 0;
    for (int j = head[v]; j != -1; j = nxt[j], ++B)
        if (B == lane) myj = j;

    if (B <= 64) {
        int myc1 = (myj >= 0) ? c1[myj] : -1;
        bool keep = (myj >= 0) && (myc1 != u);
        int rank = 0;
        for (int q = 0; q < B; ++q) {
            int jq = __shfl(myj, q);
            int cq = __shfl(myc1, q);
            if (cq != u && jq < myj) ++rank;
        }
        if (keep) {
            outRows[base + rank] = (float)i;
            outCols[base + rank] = (float)myj;
        }
    } else {
        int pos = 0;
        for (int j = head[v]; j != -1; j = nxt[j], ++pos) {
            if ((pos & 63) != lane) continue;
            if (c1[j] == u) continue;
            int rank = 0;
            for (int j2 = head[v]; j2 != -1; j2 = nxt[j2])
                rank += (c1[j2] != u && j2 < j) ? 1 : 0;
            outRows[base + rank] = (float)i;
            outCols[base + rank] = (float)j;
        }
    }

    // attr: cnt identical copies of new_x[v]; 2 rows per store instruction
    float4 val = ((const float4*)(newx + (size_t)v * DF))[lane & 31];
    for (int tt = (lane >> 5); tt < cnt; tt += 2)
        ((float4*)(outAttr + (size_t)(base + tt) * DF))[lane & 31] = val;
}

// ---------------------------------------------------------------------------

extern "C" void kernel_launch(void* const* d_in, const int* in_sizes, int n_in,
                              void* d_out, int out_size, void* d_ws, size_t ws_size,
                              hipStream_t stream) {
    const float* x  = (const float*)d_in[0];
    const float* ea = (const float*)d_in[1];
    const int*   ei = (const int*)d_in[2];
    const int* c0 = ei;        // edge_index[0]
    const int* c1 = ei + NE;   // edge_index[1]

    float* out = (float*)d_out;
    int E_lg = (out_size - NE * DF) / (DF + 2);
    if (E_lg < 0) E_lg = 0;

    float* out_newx = out;                      // NE*DF
    float* out_rows = out + (size_t)NE * DF;    // E_lg
    float* out_cols = out_rows + E_lg;          // E_lg
    float* out_attr = out_cols + E_lg;          // E_lg*DF

    int* ws       = (int*)d_ws;
    int* head     = ws;                         // NN
    int* nxt      = head + NN;                  // NE
    int* rowStart = nxt + NE;                   // NE+1
    int* gFlag    = rowStart + NE + 1;          // NBLK

    k_init<<<(NN + SB - 1) / SB, SB, 0, stream>>>(head, gFlag);
    k_link<<<(NE + SB - 1) / SB, SB, 0, stream>>>(c0, head, nxt);
    k_scan_newx<<<NBLK + NEWXB, SB, 0, stream>>>(x, ea, c0, c1, head, nxt,
                                                 gFlag, rowStart, out_newx);
    k_emit<<<(NE * 64 + SB - 1) / SB, SB, 0, stream>>>(out_newx, c0, c1, head, nxt,
                                                       rowStart, out_rows, out_cols, out_attr);
}